// Round 1
// baseline (407.810 us; speedup 1.0000x reference)
//
#include <hip/hip_runtime.h>

#define NCLS   50000
#define NC4    12500      // NCLS/4
#define BATCH  128
#define PPARTS 6
#define NROWS  768        // PPARTS*BATCH
#define FD     1536       // PPARTS*256

__device__ __forceinline__ float wave_sum(float v) {
#pragma unroll
  for (int off = 32; off > 0; off >>= 1) v += __shfl_xor(v, off, 64);
  return v;
}

// ---------------------------------------------------------------- zero acc
__global__ void zero_k(float* acc) {
  if (threadIdx.x < 8) acc[threadIdx.x] = 0.0f;
}

// ------------------------------------------------ fused CE + KL over big rows
// one block per (p,b) row; single streaming pass over x and soft_labels
__global__ __launch_bounds__(256) void big_rows_k(
    const float* __restrict__ X, const float* __restrict__ S,
    const float* __restrict__ W, const int* __restrict__ labels,
    float* __restrict__ acc) {
  const int row = blockIdx.x;
  const int b = row & (BATCH - 1);
  const int t = threadIdx.x;
  const size_t base = (size_t)row * NCLS;
  const float4* x4 = (const float4*)(X + base);
  const float4* s4 = (const float4*)(S + base);
  const float i3 = 1.0f / 3.0f;

  float x_lab = 0.0f;
  if (t == 0) x_lab = X[base + labels[b]];

  // online max-rescaled accumulators
  float m = -1e30f, e1 = 0.0f, e2 = 0.0f;
  float sx = 0.0f, ss = 0.0f, ssl = 0.0f, ssx = 0.0f;

  for (int i = t; i < NC4; i += 256) {
    float4 xv = x4[i];
    float4 sv = s4[i];
    float xs[4] = {xv.x, xv.y, xv.z, xv.w};
    float sc[4] = {sv.x, sv.y, sv.z, sv.w};
#pragma unroll
    for (int c = 0; c < 4; ++c) {
      float x = xs[c], s = sc[c];
      if (x > m) {                       // rare: rescale running sums
        float d = m - x;
        e1 *= __expf(d);
        e2 *= __expf(d * i3);
        m = x;
      }
      float d = x - m;
      e1 += __expf(d);
      e2 += __expf(d * i3);
      sx += x;
      ss += s;
      ssl = fmaf(s, __logf(s), ssl);
      ssx = fmaf(s, x, ssx);
    }
  }

  // wave reduction with max-rescale
#pragma unroll
  for (int off = 32; off > 0; off >>= 1) {
    float mo  = __shfl_xor(m, off, 64);
    float e1o = __shfl_xor(e1, off, 64);
    float e2o = __shfl_xor(e2, off, 64);
    float nm = fmaxf(m, mo);
    e1 = e1 * __expf(m - nm) + e1o * __expf(mo - nm);
    e2 = e2 * __expf((m - nm) * i3) + e2o * __expf((mo - nm) * i3);
    m = nm;
    sx  += __shfl_xor(sx, off, 64);
    ss  += __shfl_xor(ss, off, 64);
    ssl += __shfl_xor(ssl, off, 64);
    ssx += __shfl_xor(ssx, off, 64);
  }

  __shared__ float rm[4], re1[4], re2[4], rsx[4], rss[4], rssl[4], rssx[4];
  const int lane = t & 63, wid = t >> 6;
  if (lane == 0) {
    rm[wid] = m; re1[wid] = e1; re2[wid] = e2;
    rsx[wid] = sx; rss[wid] = ss; rssl[wid] = ssl; rssx[wid] = ssx;
  }
  __syncthreads();
  if (t == 0) {
    float M = rm[0], E1 = re1[0], E2 = re2[0];
#pragma unroll
    for (int wv = 1; wv < 4; ++wv) {
      float nm = fmaxf(M, rm[wv]);
      E1 = E1 * __expf(M - nm) + re1[wv] * __expf(rm[wv] - nm);
      E2 = E2 * __expf((M - nm) * i3) + re2[wv] * __expf((rm[wv] - nm) * i3);
      M = nm;
    }
    float SX  = rsx[0] + rsx[1] + rsx[2] + rsx[3];
    float SS  = rss[0] + rss[1] + rss[2] + rss[3];
    float SSL = rssl[0] + rssl[1] + rssl[2] + rssl[3];
    float SSX = rssx[0] + rssx[1] + rssx[2] + rssx[3];
    float logZ  = M + __logf(E1);
    float logZT = M * i3 + __logf(E2);
    // CE with label smoothing 0.1
    float ce = 0.9f * (logZ - x_lab) + 0.1f * (logZ - SX * (1.0f / NCLS));
    // KL(s || softmax(x/T)) = sum s*log s - sum s*x/3 + logZT * sum s
    float kl = SSL - SSX * i3 + logZT * SS;
    kl = fminf(kl, 5.0f);
    atomicAdd(&acc[0], ce);
    atomicAdd(&acc[1], kl * W[row]);
  }
}

// ---------------------------------------------- normalize concat features
// grid = 256 blocks: [src(2) x batch(128)]; concat F[b][p*256+d] then L2-norm
__global__ __launch_bounds__(256) void normalize_k(
    const float* __restrict__ idf, const float* __restrict__ grayf,
    float* __restrict__ Fn, float* __restrict__ Gn) {
  const int src = blockIdx.x >> 7;
  const int b = blockIdx.x & (BATCH - 1);
  const int t = threadIdx.x;
  const float* in = src ? grayf : idf;
  float* out = src ? Gn : Fn;

  float v[6];
  float sq = 0.0f;
#pragma unroll
  for (int k = 0; k < 6; ++k) {           // k == part index p
    v[k] = in[((k * BATCH + b) << 8) + t];
    sq = fmaf(v[k], v[k], sq);
  }
  sq = wave_sum(sq);
  __shared__ float wsum[4];
  __shared__ float inv_s;
  const int lane = t & 63, wid = t >> 6;
  if (lane == 0) wsum[wid] = sq;
  __syncthreads();
  if (t == 0) inv_s = 1.0f / sqrtf(wsum[0] + wsum[1] + wsum[2] + wsum[3]);
  __syncthreads();
  float inv = inv_s;
#pragma unroll
  for (int k = 0; k < 6; ++k)
    out[b * FD + (k << 8) + t] = v[k] * inv;
}

// --------------------------------------------- pairwise distances via Gram
// rows normalized => sq = 2 - 2*dot ; grid (8,8,2), block (16,16)
__global__ __launch_bounds__(256) void dist_k(
    const float* __restrict__ Fn, const float* __restrict__ Gn,
    float* __restrict__ D) {
  const int z = blockIdx.z;
  const float* Bm = z ? Gn : Fn;
  const int i0 = blockIdx.y * 16, j0 = blockIdx.x * 16;
  const int tx = threadIdx.x, ty = threadIdx.y;
  __shared__ float As[16][17], Bs[16][17];
  float acc = 0.0f;
  for (int k0 = 0; k0 < FD; k0 += 16) {
    As[ty][tx] = Fn[(i0 + ty) * FD + k0 + tx];
    Bs[ty][tx] = Bm[(j0 + ty) * FD + k0 + tx];
    __syncthreads();
#pragma unroll
    for (int k = 0; k < 16; ++k) acc = fmaf(As[ty][k], Bs[tx][k], acc);
    __syncthreads();
  }
  float sq = fmaxf(2.0f - 2.0f * acc, 0.0f) + 1e-12f;
  D[z * BATCH * BATCH + (i0 + ty) * BATCH + j0 + tx] = sqrtf(sq);
}

// ------------------------------------------------------- hard mining
__global__ void mine_k(const float* __restrict__ D,
                       const int* __restrict__ labels, float* __restrict__ acc) {
  const int b = threadIdx.x;  // 128 threads
  __shared__ int slab[BATCH];
  slab[b] = labels[b];
  __syncthreads();
  const int lb = slab[b];
  const float* d1 = D + b * BATCH;
  const float* d2 = D + BATCH * BATCH + b * BATCH;
  float ap1 = -1e30f, an1 = 1e30f, ap2 = -1e30f, an2 = 1e30f;
  int hasp1 = 0, hasn = 0, hasp2 = 0;
  for (int j = 0; j < BATCH; ++j) {
    bool eq = (slab[j] == lb);
    float v1 = d1[j], v2 = d2[j];
    if (eq) {
      hasp2 = 1; ap2 = fmaxf(ap2, v2);
      if (j != b) { hasp1 = 1; ap1 = fmaxf(ap1, v1); }
    } else {
      hasn = 1; an1 = fminf(an1, v1); an2 = fminf(an2, v2);
    }
  }
  float dap1 = hasp1 ? ap1 : 0.0f;
  float dan1 = hasn ? an1 : 1e6f;
  float l1 = fmaxf(dap1 - dan1 + 0.3f, 0.0f);
  float dap2 = hasp2 ? ap2 : 0.0f;
  float dan2 = hasn ? an2 : 1e6f;
  float l2 = fmaxf(dap2 - dan2 + 0.3f, 0.0f);
  l1 = wave_sum(l1);
  l2 = wave_sum(l2);
  __shared__ float r1[2], r2[2];
  const int lane = b & 63, wid = b >> 6;
  if (lane == 0) { r1[wid] = l1; r2[wid] = l2; }
  __syncthreads();
  if (b == 0) { acc[2] = r1[0] + r1[1]; acc[3] = r2[0] + r2[1]; }
}

// ------------------------------------------------------- adversarial CE
__global__ void adv_k(const float* __restrict__ advl,
                      const int* __restrict__ mod, float* __restrict__ acc) {
  const int t = threadIdx.x;  // 256 threads, 3 rows each
  float sum = 0.0f;
#pragma unroll
  for (int k = 0; k < 3; ++k) {
    int r = t + k * 256;              // 0..767
    int b = r & (BATCH - 1);
    float l0 = advl[2 * r], l1 = advl[2 * r + 1];
    float mx = fmaxf(l0, l1);
    float lse = mx + __logf(__expf(l0 - mx) + __expf(l1 - mx));
    sum += lse - (mod[b] ? l1 : l0);
  }
  sum = wave_sum(sum);
  __shared__ float rs[4];
  const int lane = t & 63, wid = t >> 6;
  if (lane == 0) rs[wid] = sum;
  __syncthreads();
  if (t == 0) acc[4] = rs[0] + rs[1] + rs[2] + rs[3];
}

// ------------------------------------------------------- final combine
__global__ void fin_k(const float* __restrict__ acc,
                      const int* __restrict__ epoch, float* __restrict__ out) {
  float L_id = acc[0] * (1.0f / NROWS);
  float L_tri = acc[2] * (1.0f / BATCH) + 0.5f * acc[3] * (1.0f / BATCH);
  float L_graph = (epoch[0] >= 20) ? acc[1] * (9.0f / (6.0f * BATCH)) : 0.0f;
  float L_adv = acc[4] * (1.0f / NROWS);
  out[0] = L_id + 1.0f * L_tri + 0.1f * L_graph + 0.1f * L_adv;
}

extern "C" void kernel_launch(void* const* d_in, const int* in_sizes, int n_in,
                              void* d_out, int out_size, void* d_ws, size_t ws_size,
                              hipStream_t stream) {
  (void)in_sizes; (void)n_in; (void)out_size; (void)ws_size;
  const float* id_logits = (const float*)d_in[0];
  const float* id_feat   = (const float*)d_in[1];
  const float* gray_feat = (const float*)d_in[2];
  const float* soft      = (const float*)d_in[3];
  const float* entw      = (const float*)d_in[4];
  const float* advl      = (const float*)d_in[5];
  const int*   labels    = (const int*)d_in[6];
  const int*   modality  = (const int*)d_in[7];
  const int*   epoch     = (const int*)d_in[8];
  float* out = (float*)d_out;

  float* acc = (float*)d_ws;          // 8 accumulator floats (+pad)
  float* Fn  = acc + 16;              // [128][1536]
  float* Gn  = Fn + BATCH * FD;       // [128][1536]
  float* D   = Gn + BATCH * FD;       // [2][128][128]

  zero_k<<<1, 64, 0, stream>>>(acc);
  big_rows_k<<<NROWS, 256, 0, stream>>>(id_logits, soft, entw, labels, acc);
  normalize_k<<<256, 256, 0, stream>>>(id_feat, gray_feat, Fn, Gn);
  dist_k<<<dim3(8, 8, 2), dim3(16, 16), 0, stream>>>(Fn, Gn, D);
  mine_k<<<1, BATCH, 0, stream>>>(D, labels, acc);
  adv_k<<<1, 256, 0, stream>>>(advl, modality, acc);
  fin_k<<<1, 1, 0, stream>>>(acc, epoch, out);
}